// Round 12
// baseline (212.548 us; speedup 1.0000x reference)
//
#include <hip/hip_runtime.h>
#include <hip/hip_bf16.h>

#define B_ 32
#define S_ 64
#define H_ 300
#define H2_ 600
#define L_ 20
#define ROW_ 160                    // 8 pieces * 20
#define OUTQ_OFF ((size_t)B_ * S_ * ROW_)
#define NEG_INF -3.402823466e38f

// ---------------- K0: w^2 tables + zero sum_p (atomic target in k_cos)
__global__ void k_w2(const float* __restrict__ Wf, float* __restrict__ w2,
                     float* __restrict__ w2t, float* __restrict__ sum_p) {
  int i = blockIdx.x * 256 + threadIdx.x;
  if (i < 8 * L_ * H_) {
    float v = Wf[i];
    float v2 = v * v;
    w2[i] = v2;
    int widx = i / (L_ * H_);
    int r = i - widx * (L_ * H_);
    int l = r / H_;
    int h = r - l * H_;
    w2t[widx * (L_ * H_) + h * L_ + l] = v2;
  }
  if (i < B_ * 2 * S_) sum_p[i] = 0.f;
}

// ---------------- K1: cosine matrix, block = (bd, 16-row p-group) (r10/r11: pass)
__global__ __launch_bounds__(256) void k_cos(const float* __restrict__ P,
                                             const float* __restrict__ Q,
                                             float* __restrict__ cosM,
                                             float* __restrict__ sum_p,
                                             float* __restrict__ sum_q) {
  int bd = blockIdx.x;
  int pg = blockIdx.y;
  int p0 = pg * 16;
  int b = bd >> 1, dir = bd & 1;
  __shared__ float xp[16][101];
  __shared__ float xq[S_][101];
  __shared__ float pn[16], qn[S_];
  __shared__ float cosL[16][S_ + 1];
  int t = threadIdx.x;
  int q = t & 63, pr = t >> 6;
  float dot[4] = {0.f, 0.f, 0.f, 0.f};
  float np2 = 0.f, nq2 = 0.f;
  const float* Pb = P + (size_t)b * S_ * H2_ + dir * H_;
  const float* Qb = Q + (size_t)b * S_ * H2_ + dir * H_;
  for (int c0 = 0; c0 < H_; c0 += 100) {
    __syncthreads();
    for (int idx = t; idx < 16 * 100; idx += 256) {
      int s = idx / 100, hh = idx - s * 100;
      xp[s][hh] = Pb[(size_t)(p0 + s) * H2_ + c0 + hh];
    }
    for (int idx = t; idx < S_ * 100; idx += 256) {
      int s = idx / 100, hh = idx - s * 100;
      xq[s][hh] = Qb[(size_t)s * H2_ + c0 + hh];
    }
    __syncthreads();
    for (int hh = 0; hh < 100; ++hh) {
      float qv = xq[q][hh];
#pragma unroll
      for (int i = 0; i < 4; ++i) dot[i] = fmaf(xp[pr + 4 * i][hh], qv, dot[i]);
    }
    if (t < 16) {
      for (int hh = 0; hh < 100; ++hh) { float v = xp[t][hh]; np2 = fmaf(v, v, np2); }
    } else if (t >= 64 && t < 128) {
      int s2 = t - 64;
      for (int hh = 0; hh < 100; ++hh) { float v = xq[s2][hh]; nq2 = fmaf(v, v, nq2); }
    }
  }
  if (t < 16) pn[t] = sqrtf(np2);
  else if (t >= 64 && t < 128) qn[t - 64] = sqrtf(nq2);
  __syncthreads();
  float* cm = cosM + (size_t)bd * S_ * S_;
#pragma unroll
  for (int i = 0; i < 4; ++i) {
    int p = pr + 4 * i;
    float c = dot[i] / (pn[p] * qn[q]);
    cosL[p][q] = c;
    cm[(size_t)(p0 + p) * S_ + q] = c;
  }
  __syncthreads();
  if (t < 16) {
    double acc = 0.0;
    for (int qq = 0; qq < S_; ++qq) acc += (double)cosL[t][qq];
    sum_q[bd * S_ + p0 + t] = (float)acc;
  } else if (t >= 64 && t < 128) {
    int qq = t - 64;
    float acc = 0.f;
    for (int p = 0; p < 16; ++p) acc += cosL[p][qq];
    atomicAdd(&sum_p[bd * S_ + qq], acc);
  }
}

// ======== fused main kernel — R12: both bodies <= 32 KB -> 5 blocks/CU ========
#define CW 50
struct MaxpoolS {              // 29024 B
  float xp[S_][CW];            // colm[2][16][64] (8 KB) aliases here after loop
  float xq[S_][CW];
  float w2s[2][H_];
  float pn[2][S_], qn[2][S_];
};
#define SG 4
struct OutsS {                 // 31264 B
  float u[600];                // phase B: cosC[4][64]@0, cosR[4][64]@256; phase C: tq@0, tp@300
  float xP[SG][H_], xQ[SG][H_];
  float vmq[SG][H_], vmp[SG][H_], vxq[SG][H_], vxp[SG][H_];
  float sps[SG], sqs[SG];
};

__device__ __forceinline__ void maxpool_body(char* smem, int bid,
                                             const float* __restrict__ P,
                                             const float* __restrict__ Q,
                                             const float* __restrict__ w2,
                                             float* __restrict__ out) {
  MaxpoolS& S = *(MaxpoolS*)smem;
  int lg = bid % 10;
  int bd = bid / 10;
  int b = bd >> 1, dir = bd & 1;
  int l0 = lg * 2;
  int t = threadIdx.x;
  int pi = t >> 4, qi = t & 15;
  float (*colm)[16][S_] = (float (*)[16][S_])&S.xp[0][0];   // 2048 floats <= 3200
  const float* w2g = w2 + (size_t)(2 + dir) * L_ * H_ + (size_t)l0 * H_;
  for (int idx = t; idx < 2 * H_; idx += 256) S.w2s[idx / H_][idx % H_] = w2g[idx];
  float dot[2][16];
#pragma unroll
  for (int l = 0; l < 2; ++l)
#pragma unroll
    for (int k = 0; k < 16; ++k) dot[l][k] = 0.f;
  float np2[2] = {0.f, 0.f}, nq2[2] = {0.f, 0.f};
  const float* Pb = P + (size_t)b * S_ * H2_ + dir * H_;
  const float* Qb = Q + (size_t)b * S_ * H2_ + dir * H_;
  for (int c0 = 0; c0 < H_; c0 += CW) {     // 300 = 6 * 50, exact
    __syncthreads();
    for (int idx = t; idx < S_ * CW; idx += 256) {
      int s = idx / CW, hh = idx - s * CW;
      S.xp[s][hh] = Pb[(size_t)s * H2_ + c0 + hh];
      S.xq[s][hh] = Qb[(size_t)s * H2_ + c0 + hh];
    }
    __syncthreads();
    for (int hh = 0; hh < CW; ++hh) {
      float w0 = S.w2s[0][c0 + hh], w1 = S.w2s[1][c0 + hh];
      float pv[4], qv[4];
#pragma unroll
      for (int i = 0; i < 4; ++i) pv[i] = S.xp[pi + 16 * i][hh];
#pragma unroll
      for (int j = 0; j < 4; ++j) qv[j] = S.xq[qi + 16 * j][hh];
      float p0[4], p1[4];
#pragma unroll
      for (int i = 0; i < 4; ++i) { p0[i] = pv[i] * w0; p1[i] = pv[i] * w1; }
#pragma unroll
      for (int i = 0; i < 4; ++i)
#pragma unroll
        for (int j = 0; j < 4; ++j) {
          dot[0][i * 4 + j] = fmaf(p0[i], qv[j], dot[0][i * 4 + j]);
          dot[1][i * 4 + j] = fmaf(p1[i], qv[j], dot[1][i * 4 + j]);
        }
    }
    if (t < S_) {
      for (int hh = 0; hh < CW; ++hh) {
        float v = S.xp[t][hh], vv = v * v;
        np2[0] = fmaf(S.w2s[0][c0 + hh], vv, np2[0]);
        np2[1] = fmaf(S.w2s[1][c0 + hh], vv, np2[1]);
      }
    } else if (t < 2 * S_) {
      int s2 = t - S_;
      for (int hh = 0; hh < CW; ++hh) {
        float v = S.xq[s2][hh], vv = v * v;
        nq2[0] = fmaf(S.w2s[0][c0 + hh], vv, nq2[0]);
        nq2[1] = fmaf(S.w2s[1][c0 + hh], vv, nq2[1]);
      }
    }
  }
  if (t < S_) { S.pn[0][t] = sqrtf(np2[0]); S.pn[1][t] = sqrtf(np2[1]); }
  else if (t < 2 * S_) { S.qn[0][t - S_] = sqrtf(nq2[0]); S.qn[1][t - S_] = sqrtf(nq2[1]); }
  __syncthreads();
  // cos in regs; row max via shfl over the 16 consecutive qi lanes; col partials in LDS.
  float rm[2][4], cx[2][4];
#pragma unroll
  for (int l = 0; l < 2; ++l)
#pragma unroll
    for (int k = 0; k < 4; ++k) { rm[l][k] = NEG_INF; cx[l][k] = NEG_INF; }
#pragma unroll
  for (int l = 0; l < 2; ++l)
#pragma unroll
    for (int i = 0; i < 4; ++i) {
      float pnv = S.pn[l][pi + 16 * i];
#pragma unroll
      for (int j = 0; j < 4; ++j) {
        float c = dot[l][i * 4 + j] / (pnv * S.qn[l][qi + 16 * j]);   // no EPS (ref maxpool)
        rm[l][i] = fmaxf(rm[l][i], c);
        cx[l][j] = fmaxf(cx[l][j], c);
      }
    }
#pragma unroll
  for (int m = 1; m < 16; m <<= 1)
#pragma unroll
    for (int l = 0; l < 2; ++l)
#pragma unroll
      for (int i = 0; i < 4; ++i) rm[l][i] = fmaxf(rm[l][i], __shfl_xor(rm[l][i], m));
  if (qi == 0) {
#pragma unroll
    for (int i = 0; i < 4; ++i) {
      int p = pi + 16 * i;
      size_t base = ((size_t)b * S_ + p) * ROW_ + (2 + dir) * L_ + l0;
      out[base] = rm[0][i]; out[base + 1] = rm[1][i];
    }
  }
#pragma unroll
  for (int l = 0; l < 2; ++l)
#pragma unroll
    for (int j = 0; j < 4; ++j) colm[l][pi][qi + 16 * j] = cx[l][j];
  __syncthreads();
  if (t < S_) {
    float m0 = NEG_INF, m1 = NEG_INF;
#pragma unroll
    for (int k = 0; k < 16; ++k) { m0 = fmaxf(m0, colm[0][k][t]); m1 = fmaxf(m1, colm[1][k][t]); }
    size_t base = OUTQ_OFF + ((size_t)b * S_ + t) * ROW_ + (2 + dir) * L_ + l0;
    out[base] = m0; out[base + 1] = m1;
  }
}

__device__ __forceinline__ void outs_body(char* smem, int bid,
                                          const float* __restrict__ P,
                                          const float* __restrict__ Q,
                                          const float* __restrict__ w2t,
                                          const float* __restrict__ cosM,
                                          const float* __restrict__ sum_p,
                                          const float* __restrict__ sum_q,
                                          float* __restrict__ out) {
  OutsS& S = *(OutsS*)smem;
  int bd = bid >> 4;
  int sg = bid & 15;
  int s0 = sg * SG;
  int b = bd >> 1, dir = bd & 1;
  int t = threadIdx.x;
  float (*cosC)[S_] = (float (*)[S_])&S.u[0];
  float (*cosR)[S_] = (float (*)[S_])&S.u[256];
  const float* cm = cosM + (size_t)bd * S_ * S_;
  for (int idx = t; idx < SG * S_; idx += 256) {
    int si = idx >> 6, k = idx & 63;
    cosC[si][k] = cm[k * S_ + s0 + si];
    cosR[si][k] = cm[(s0 + si) * S_ + k];
  }
  if (t < SG) { S.sps[t] = sum_p[bd * S_ + s0 + t]; S.sqs[t] = sum_q[bd * S_ + s0 + t]; }
  int tgt = dir ? 0 : S_ - 1;
  const float* Pb = P + (size_t)b * S_ * H2_ + dir * H_;
  const float* Qb = Q + (size_t)b * S_ * H2_ + dir * H_;
  for (int idx = t; idx < SG * H_; idx += 256) {
    int si = idx / H_, h = idx - si * H_;
    S.xP[si][h] = Pb[(size_t)(s0 + si) * H2_ + h];
    S.xQ[si][h] = Qb[(size_t)(s0 + si) * H2_ + h];
  }
  __syncthreads();
  // Phase B: attention vectors (reads cosC/cosR from u)
  for (int h = t; h < H_; h += 256) {
    float amp[SG], amq[SG], axp[SG], axq[SG];
#pragma unroll
    for (int si = 0; si < SG; ++si) { amp[si] = 0.f; amq[si] = 0.f; axp[si] = NEG_INF; axq[si] = NEG_INF; }
    for (int k = 0; k < S_; k += 2) {
      float pv0 = Pb[(size_t)k * H2_ + h];
      float qv0 = Qb[(size_t)k * H2_ + h];
      float pv1 = Pb[(size_t)(k + 1) * H2_ + h];
      float qv1 = Qb[(size_t)(k + 1) * H2_ + h];
#pragma unroll
      for (int si = 0; si < SG; ++si) {
        float t1 = pv0 * cosC[si][k];
        amp[si] += t1; axp[si] = fmaxf(axp[si], t1);
        float t2 = qv0 * cosR[si][k];
        amq[si] += t2; axq[si] = fmaxf(axq[si], t2);
        float t3 = pv1 * cosC[si][k + 1];
        amp[si] += t3; axp[si] = fmaxf(axp[si], t3);
        float t4 = qv1 * cosR[si][k + 1];
        amq[si] += t4; axq[si] = fmaxf(axq[si], t4);
      }
    }
#pragma unroll
    for (int si = 0; si < SG; ++si) {
      S.vmq[si][h] = amq[si] / S.sqs[si];
      S.vmp[si][h] = amp[si] / S.sps[si];
      S.vxq[si][h] = axq[si];
      S.vxp[si][h] = axp[si];
    }
  }
  __syncthreads();
  // Reload u as tq/tp (cosC/cosR dead after phase B)
  float* tq = &S.u[0];
  float* tp = &S.u[300];
  for (int h = t; h < H_; h += 256) { tq[h] = Qb[(size_t)tgt * H2_ + h]; tp[h] = Pb[(size_t)tgt * H2_ + h]; }
  __syncthreads();
  // Phase C: 480 jobs = 240 threads * 2
  if (t < 240) {
    const int wb_[6] = {0, 0, 4, 4, 6, 6};
#pragma unroll
    for (int r = 0; r < 2; ++r) {
      int job = t + 240 * r;
      int l = job % L_;
      int g = job / L_;
      int pr = g % 6, si = g / 6;
      const float* x = (pr & 1) ? S.xQ[si] : S.xP[si];
      const float* y;
      if (pr == 0) y = tq;
      else if (pr == 1) y = tp;
      else if (pr == 2) y = S.vmq[si];
      else if (pr == 3) y = S.vmp[si];
      else if (pr == 4) y = S.vxq[si];
      else y = S.vxp[si];
      int widx = wb_[pr] + dir;
      const float* wp = w2t + (size_t)widx * (L_ * H_) + l;
      float a1 = 0.f, a2 = 0.f, a3 = 0.f;
      for (int h = 0; h < H_; ++h) {
        float wv = wp[h * L_];
        float xx = x[h], yy = y[h];
        float wx = wv * xx;
        a1 = fmaf(wx, yy, a1);
        a2 = fmaf(wx, xx, a2);
        a3 = fmaf(wv * yy, yy, a3);
      }
      float den = fmaxf(sqrtf(a2) * sqrtf(a3), 1e-8f);   // EPS per _mp_cos
      float c = a1 / den;
      int s = s0 + si;
      size_t base = ((pr & 1) ? OUTQ_OFF : 0) + ((size_t)b * S_ + s) * ROW_;
      out[base + (size_t)widx * L_ + l] = c;
    }
  }
}

__global__ __launch_bounds__(256) void k_main(const float* __restrict__ P,
                                              const float* __restrict__ Q,
                                              const float* __restrict__ w2,
                                              const float* __restrict__ w2t,
                                              const float* __restrict__ cosM,
                                              const float* __restrict__ sum_p,
                                              const float* __restrict__ sum_q,
                                              float* __restrict__ out) {
  extern __shared__ char smem[];
  int bid = blockIdx.x;
  if (bid < B_ * 2 * 10) maxpool_body(smem, bid, P, Q, w2, out);
  else outs_body(smem, bid - B_ * 2 * 10, P, Q, w2t, cosM, sum_p, sum_q, out);
}

extern "C" void kernel_launch(void* const* d_in, const int* in_sizes, int n_in,
                              void* d_out, int out_size, void* d_ws, size_t ws_size,
                              hipStream_t stream) {
  (void)out_size; (void)ws_size;
  int iw = 2;
  for (int i = 0; i < n_in; ++i) if (in_sizes[i] == 8 * L_ * H_) iw = i;
  int io[2] = {0, 1}, k = 0;
  for (int i = 0; i < n_in && k < 2; ++i) if (i != iw) io[k++] = i;
  const float* P  = (const float*)d_in[io[0]];
  const float* Q  = (const float*)d_in[io[1]];
  const float* Wf = (const float*)d_in[iw];
  float* out = (float*)d_out;

  float* ws = (float*)d_ws;         // ~1.46 MB
  float* w2    = ws;                // 48000
  float* w2t   = w2 + 48000;        // 48000
  float* cosM  = w2t + 48000;       // 262144
  float* sum_p = cosM + 262144;     // 4096 (zeroed by k_w2, atomic target)
  float* sum_q = sum_p + 4096;      // 4096

  size_t shbytes = sizeof(MaxpoolS) > sizeof(OutsS) ? sizeof(MaxpoolS) : sizeof(OutsS);
  k_w2<<<(8 * L_ * H_ + 255) / 256, 256, 0, stream>>>(Wf, w2, w2t, sum_p);
  k_cos<<<dim3(B_ * 2, 4), 256, 0, stream>>>(P, Q, cosM, sum_p, sum_q);
  k_main<<<B_ * 2 * 10 + B_ * 2 * 16, 256, shbytes, stream>>>(P, Q, w2, w2t, cosM, sum_p, sum_q, out);
}

// Round 13
// 204.396 us; speedup vs baseline: 1.0399x; 1.0399x over previous
//
#include <hip/hip_runtime.h>
#include <hip/hip_bf16.h>

#define B_ 32
#define S_ 64
#define H_ 300
#define H2_ 600
#define L_ 20
#define ROW_ 160                    // 8 pieces * 20
#define OUTQ_OFF ((size_t)B_ * S_ * ROW_)
#define NEG_INF -3.402823466e38f

typedef __attribute__((ext_vector_type(8))) short short8v;   // 8 bf16 = 4 VGPRs
typedef __attribute__((ext_vector_type(4))) float float4v;

__device__ __forceinline__ short f2bf(float x) {   // RNE float->bf16 bits
  unsigned u = __float_as_uint(x);
  u += 0x7fffu + ((u >> 16) & 1u);
  return (short)(u >> 16);
}
__device__ __forceinline__ float bf2f_(short s) {
  return __uint_as_float(((unsigned)(unsigned short)s) << 16);
}

// ---------------- K0: w2t (transposed w^2 for outs) + w1 (|W| for mfma maxpool) + zero sum_p
__global__ void k_w2(const float* __restrict__ Wf, float* __restrict__ w2t,
                     float* __restrict__ w1, float* __restrict__ sum_p) {
  int i = blockIdx.x * 256 + threadIdx.x;
  if (i < 8 * L_ * H_) {
    float v = Wf[i];
    float v2 = v * v;
    w1[i] = fabsf(v);
    int widx = i / (L_ * H_);
    int r = i - widx * (L_ * H_);
    int l = r / H_;
    int h = r - l * H_;
    w2t[widx * (L_ * H_) + h * L_ + l] = v2;
  }
  if (i < B_ * 2 * S_) sum_p[i] = 0.f;
}

// ---------------- K1: cosine matrix, block = (bd, 16-row p-group) (r10-12: pass)
__global__ __launch_bounds__(256) void k_cos(const float* __restrict__ P,
                                             const float* __restrict__ Q,
                                             float* __restrict__ cosM,
                                             float* __restrict__ sum_p,
                                             float* __restrict__ sum_q) {
  int bd = blockIdx.x;
  int pg = blockIdx.y;
  int p0 = pg * 16;
  int b = bd >> 1, dir = bd & 1;
  __shared__ float xp[16][101];
  __shared__ float xq[S_][101];
  __shared__ float pn[16], qn[S_];
  __shared__ float cosL[16][S_ + 1];
  int t = threadIdx.x;
  int q = t & 63, pr = t >> 6;
  float dot[4] = {0.f, 0.f, 0.f, 0.f};
  float np2 = 0.f, nq2 = 0.f;
  const float* Pb = P + (size_t)b * S_ * H2_ + dir * H_;
  const float* Qb = Q + (size_t)b * S_ * H2_ + dir * H_;
  for (int c0 = 0; c0 < H_; c0 += 100) {
    __syncthreads();
    for (int idx = t; idx < 16 * 100; idx += 256) {
      int s = idx / 100, hh = idx - s * 100;
      xp[s][hh] = Pb[(size_t)(p0 + s) * H2_ + c0 + hh];
    }
    for (int idx = t; idx < S_ * 100; idx += 256) {
      int s = idx / 100, hh = idx - s * 100;
      xq[s][hh] = Qb[(size_t)s * H2_ + c0 + hh];
    }
    __syncthreads();
    for (int hh = 0; hh < 100; ++hh) {
      float qv = xq[q][hh];
#pragma unroll
      for (int i = 0; i < 4; ++i) dot[i] = fmaf(xp[pr + 4 * i][hh], qv, dot[i]);
    }
    if (t < 16) {
      for (int hh = 0; hh < 100; ++hh) { float v = xp[t][hh]; np2 = fmaf(v, v, np2); }
    } else if (t >= 64 && t < 128) {
      int s2 = t - 64;
      for (int hh = 0; hh < 100; ++hh) { float v = xq[s2][hh]; nq2 = fmaf(v, v, nq2); }
    }
  }
  if (t < 16) pn[t] = sqrtf(np2);
  else if (t >= 64 && t < 128) qn[t - 64] = sqrtf(nq2);
  __syncthreads();
  float* cm = cosM + (size_t)bd * S_ * S_;
#pragma unroll
  for (int i = 0; i < 4; ++i) {
    int p = pr + 4 * i;
    float c = dot[i] / (pn[p] * qn[q]);
    cosL[p][q] = c;
    cm[(size_t)(p0 + p) * S_ + q] = c;
  }
  __syncthreads();
  if (t < 16) {
    double acc = 0.0;
    for (int qq = 0; qq < S_; ++qq) acc += (double)cosL[t][qq];
    sum_q[bd * S_ + p0 + t] = (float)acc;
  } else if (t >= 64 && t < 128) {
    int qq = t - 64;
    float acc = 0.f;
    for (int p = 0; p < 16; ++p) acc += cosL[p][qq];
    atomicAdd(&sum_p[bd * S_ + qq], acc);
  }
}

// ======== fused main kernel — R13: maxpool on MFMA (split-bf16), 1 l/block ========
#define HP 72                       // padded row: 144 B (16-B aligned), 36-dword stride
struct MaxpoolS {                   // 39600 B
  short ph[S_][HP], pl[S_][HP];     // w-scaled P, bf16 hi/lo
  short qh[S_][HP], ql[S_][HP];     // w-scaled Q, bf16 hi/lo
  float w1s[H_];
  float pn[S_], qn[S_];
  float colp[4][S_];
};
#define SG 4
struct OutsS {                      // 31264 B (r12, unchanged)
  float u[600];
  float xP[SG][H_], xQ[SG][H_];
  float vmq[SG][H_], vmp[SG][H_], vxq[SG][H_], vxp[SG][H_];
  float sps[SG], sqs[SG];
};

__device__ __forceinline__ void maxpool_body(char* smem, int bid,
                                             const float* __restrict__ P,
                                             const float* __restrict__ Q,
                                             const float* __restrict__ w1,
                                             float* __restrict__ out) {
  MaxpoolS& S = *(MaxpoolS*)smem;
  int l = bid % L_;
  int bd = bid / L_;
  int b = bd >> 1, dir = bd & 1;
  int t = threadIdx.x;
  int w = t >> 6, lane = t & 63, quad = lane >> 4, col = lane & 15;
  const float* w1g = w1 + (size_t)(2 + dir) * L_ * H_ + (size_t)l * H_;
  for (int idx = t; idx < H_; idx += 256) S.w1s[idx] = w1g[idx];
  const float* Pb = P + (size_t)b * S_ * H2_ + dir * H_;
  const float* Qb = Q + (size_t)b * S_ * H2_ + dir * H_;
  float4v acc[4];
#pragma unroll
  for (int qt = 0; qt < 4; ++qt) acc[qt] = (float4v){0.f, 0.f, 0.f, 0.f};
  float np2 = 0.f, nq2 = 0.f;
  for (int h0 = 0; h0 < H_; h0 += 64) {          // 5 chunks (last padded w/ zeros)
    __syncthreads();
    for (int idx = t; idx < S_ * 64; idx += 256) {
      int s = idx >> 6, hh = idx & 63, h = h0 + hh;
      float pv = 0.f, qv = 0.f;
      if (h < H_) {
        float wv = S.w1s[h];
        pv = Pb[(size_t)s * H2_ + h] * wv;
        qv = Qb[(size_t)s * H2_ + h] * wv;
      }
      short phi = f2bf(pv), qhi = f2bf(qv);
      S.ph[s][hh] = phi; S.pl[s][hh] = f2bf(pv - bf2f_(phi));
      S.qh[s][hh] = qhi; S.ql[s][hh] = f2bf(qv - bf2f_(qhi));
    }
    __syncthreads();
#pragma unroll
    for (int ks = 0; ks < 2; ++ks) {
      short8v ah = *(const short8v*)&S.ph[16 * w + col][ks * 32 + quad * 8];
      short8v al = *(const short8v*)&S.pl[16 * w + col][ks * 32 + quad * 8];
#pragma unroll
      for (int qt = 0; qt < 4; ++qt) {
        short8v bh = *(const short8v*)&S.qh[16 * qt + col][ks * 32 + quad * 8];
        short8v bl = *(const short8v*)&S.ql[16 * qt + col][ks * 32 + quad * 8];
        acc[qt] = __builtin_amdgcn_mfma_f32_16x16x32_bf16(ah, bh, acc[qt], 0, 0, 0);
        acc[qt] = __builtin_amdgcn_mfma_f32_16x16x32_bf16(ah, bl, acc[qt], 0, 0, 0);
        acc[qt] = __builtin_amdgcn_mfma_f32_16x16x32_bf16(al, bh, acc[qt], 0, 0, 0);
      }
    }
    if (t < S_) {               // np2 = sum (w*P)^2 from hi+lo (exact to 2^-17)
      for (int hh = 0; hh < 64; ++hh) {
        float v = bf2f_(S.ph[t][hh]) + bf2f_(S.pl[t][hh]);
        np2 = fmaf(v, v, np2);
      }
    } else if (t < 2 * S_) {
      int s2 = t - S_;
      for (int hh = 0; hh < 64; ++hh) {
        float v = bf2f_(S.qh[s2][hh]) + bf2f_(S.ql[s2][hh]);
        nq2 = fmaf(v, v, nq2);
      }
    }
  }
  if (t < S_) S.pn[t] = sqrtf(np2);
  else if (t < 2 * S_) S.qn[t - S_] = sqrtf(nq2);
  __syncthreads();
  // cos + row/col maxes. C/D: row = quad*4+r (p_local), col = lane&15 (q_local).
  float pnv[4];
#pragma unroll
  for (int r = 0; r < 4; ++r) pnv[r] = S.pn[16 * w + quad * 4 + r];
  float rowm[4] = {NEG_INF, NEG_INF, NEG_INF, NEG_INF};
#pragma unroll
  for (int qt = 0; qt < 4; ++qt) {
    float qnv = S.qn[16 * qt + col];
    float cm = NEG_INF;
#pragma unroll
    for (int r = 0; r < 4; ++r) {
      float c = acc[qt][r] / (pnv[r] * qnv);    // no EPS in reference maxpool
      rowm[r] = fmaxf(rowm[r], c);
      cm = fmaxf(cm, c);
    }
    cm = fmaxf(cm, __shfl_xor(cm, 16));         // reduce across quads (rows)
    cm = fmaxf(cm, __shfl_xor(cm, 32));
    if (quad == 0) S.colp[w][16 * qt + col] = cm;
  }
#pragma unroll
  for (int m = 1; m < 16; m <<= 1)
#pragma unroll
    for (int r = 0; r < 4; ++r) rowm[r] = fmaxf(rowm[r], __shfl_xor(rowm[r], m));
  if (col == 0) {
#pragma unroll
    for (int r = 0; r < 4; ++r) {
      int p = 16 * w + quad * 4 + r;
      out[((size_t)b * S_ + p) * ROW_ + (2 + dir) * L_ + l] = rowm[r];
    }
  }
  __syncthreads();
  if (t < S_) {
    float m0 = fmaxf(fmaxf(S.colp[0][t], S.colp[1][t]), fmaxf(S.colp[2][t], S.colp[3][t]));
    out[OUTQ_OFF + ((size_t)b * S_ + t) * ROW_ + (2 + dir) * L_ + l] = m0;
  }
}

__device__ __forceinline__ void outs_body(char* smem, int bid,
                                          const float* __restrict__ P,
                                          const float* __restrict__ Q,
                                          const float* __restrict__ w2t,
                                          const float* __restrict__ cosM,
                                          const float* __restrict__ sum_p,
                                          const float* __restrict__ sum_q,
                                          float* __restrict__ out) {
  OutsS& S = *(OutsS*)smem;
  int bd = bid >> 4;
  int sg = bid & 15;
  int s0 = sg * SG;
  int b = bd >> 1, dir = bd & 1;
  int t = threadIdx.x;
  float (*cosC)[S_] = (float (*)[S_])&S.u[0];
  float (*cosR)[S_] = (float (*)[S_])&S.u[256];
  const float* cm = cosM + (size_t)bd * S_ * S_;
  for (int idx = t; idx < SG * S_; idx += 256) {
    int si = idx >> 6, k = idx & 63;
    cosC[si][k] = cm[k * S_ + s0 + si];
    cosR[si][k] = cm[(s0 + si) * S_ + k];
  }
  if (t < SG) { S.sps[t] = sum_p[bd * S_ + s0 + t]; S.sqs[t] = sum_q[bd * S_ + s0 + t]; }
  int tgt = dir ? 0 : S_ - 1;
  const float* Pb = P + (size_t)b * S_ * H2_ + dir * H_;
  const float* Qb = Q + (size_t)b * S_ * H2_ + dir * H_;
  for (int idx = t; idx < SG * H_; idx += 256) {
    int si = idx / H_, h = idx - si * H_;
    S.xP[si][h] = Pb[(size_t)(s0 + si) * H2_ + h];
    S.xQ[si][h] = Qb[(size_t)(s0 + si) * H2_ + h];
  }
  __syncthreads();
  for (int h = t; h < H_; h += 256) {
    float amp[SG], amq[SG], axp[SG], axq[SG];
#pragma unroll
    for (int si = 0; si < SG; ++si) { amp[si] = 0.f; amq[si] = 0.f; axp[si] = NEG_INF; axq[si] = NEG_INF; }
    for (int k = 0; k < S_; k += 2) {
      float pv0 = Pb[(size_t)k * H2_ + h];
      float qv0 = Qb[(size_t)k * H2_ + h];
      float pv1 = Pb[(size_t)(k + 1) * H2_ + h];
      float qv1 = Qb[(size_t)(k + 1) * H2_ + h];
#pragma unroll
      for (int si = 0; si < SG; ++si) {
        float t1 = pv0 * cosC[si][k];
        amp[si] += t1; axp[si] = fmaxf(axp[si], t1);
        float t2 = qv0 * cosR[si][k];
        amq[si] += t2; axq[si] = fmaxf(axq[si], t2);
        float t3 = pv1 * cosC[si][k + 1];
        amp[si] += t3; axp[si] = fmaxf(axp[si], t3);
        float t4 = qv1 * cosR[si][k + 1];
        amq[si] += t4; axq[si] = fmaxf(axq[si], t4);
      }
    }
#pragma unroll
    for (int si = 0; si < SG; ++si) {
      S.vmq[si][h] = amq[si] / S.sqs[si];
      S.vmp[si][h] = amp[si] / S.sps[si];
      S.vxq[si][h] = axq[si];
      S.vxp[si][h] = axp[si];
    }
  }
  __syncthreads();
  float* tq = &S.u[0];
  float* tp = &S.u[300];
  for (int h = t; h < H_; h += 256) { tq[h] = Qb[(size_t)tgt * H2_ + h]; tp[h] = Pb[(size_t)tgt * H2_ + h]; }
  __syncthreads();
  if (t < 240) {
    const int wb_[6] = {0, 0, 4, 4, 6, 6};
#pragma unroll
    for (int r = 0; r < 2; ++r) {
      int job = t + 240 * r;
      int l = job % L_;
      int g = job / L_;
      int pr = g % 6, si = g / 6;
      const float* x = (pr & 1) ? S.xQ[si] : S.xP[si];
      const float* y;
      if (pr == 0) y = tq;
      else if (pr == 1) y = tp;
      else if (pr == 2) y = S.vmq[si];
      else if (pr == 3) y = S.vmp[si];
      else if (pr == 4) y = S.vxq[si];
      else y = S.vxp[si];
      int widx = wb_[pr] + dir;
      const float* wp = w2t + (size_t)widx * (L_ * H_) + l;
      float a1 = 0.f, a2 = 0.f, a3 = 0.f;
      for (int h = 0; h < H_; ++h) {
        float wv = wp[h * L_];
        float xx = x[h], yy = y[h];
        float wx = wv * xx;
        a1 = fmaf(wx, yy, a1);
        a2 = fmaf(wx, xx, a2);
        a3 = fmaf(wv * yy, yy, a3);
      }
      float den = fmaxf(sqrtf(a2) * sqrtf(a3), 1e-8f);   // EPS per _mp_cos
      float c = a1 / den;
      int s = s0 + si;
      size_t base = ((pr & 1) ? OUTQ_OFF : 0) + ((size_t)b * S_ + s) * ROW_;
      out[base + (size_t)widx * L_ + l] = c;
    }
  }
}

__global__ __launch_bounds__(256) void k_main(const float* __restrict__ P,
                                              const float* __restrict__ Q,
                                              const float* __restrict__ w1,
                                              const float* __restrict__ w2t,
                                              const float* __restrict__ cosM,
                                              const float* __restrict__ sum_p,
                                              const float* __restrict__ sum_q,
                                              float* __restrict__ out) {
  extern __shared__ char smem[];
  int bid = blockIdx.x;
  if (bid < B_ * 2 * L_) maxpool_body(smem, bid, P, Q, w1, out);
  else outs_body(smem, bid - B_ * 2 * L_, P, Q, w2t, cosM, sum_p, sum_q, out);
}

extern "C" void kernel_launch(void* const* d_in, const int* in_sizes, int n_in,
                              void* d_out, int out_size, void* d_ws, size_t ws_size,
                              hipStream_t stream) {
  (void)out_size; (void)ws_size;
  int iw = 2;
  for (int i = 0; i < n_in; ++i) if (in_sizes[i] == 8 * L_ * H_) iw = i;
  int io[2] = {0, 1}, k = 0;
  for (int i = 0; i < n_in && k < 2; ++i) if (i != iw) io[k++] = i;
  const float* P  = (const float*)d_in[io[0]];
  const float* Q  = (const float*)d_in[io[1]];
  const float* Wf = (const float*)d_in[iw];
  float* out = (float*)d_out;

  float* ws = (float*)d_ws;         // ~1.46 MB
  float* w2t   = ws;                // 48000
  float* w1    = w2t + 48000;       // 48000
  float* cosM  = w1 + 48000;        // 262144
  float* sum_p = cosM + 262144;     // 4096 (zeroed by k_w2, atomic target)
  float* sum_q = sum_p + 4096;      // 4096

  size_t shbytes = sizeof(MaxpoolS) > sizeof(OutsS) ? sizeof(MaxpoolS) : sizeof(OutsS);
  k_w2<<<(8 * L_ * H_ + 255) / 256, 256, 0, stream>>>(Wf, w2t, w1, sum_p);
  k_cos<<<dim3(B_ * 2, 4), 256, 0, stream>>>(P, Q, cosM, sum_p, sum_q);
  k_main<<<B_ * 2 * L_ + B_ * 2 * 16, 256, shbytes, stream>>>(P, Q, w1, w2t, cosM, sum_p, sum_q, out);
}

// Round 14
// 177.898 us; speedup vs baseline: 1.1948x; 1.1490x over previous
//
#include <hip/hip_runtime.h>
#include <hip/hip_bf16.h>

#define B_ 32
#define S_ 64
#define H_ 300
#define H2_ 600
#define L_ 20
#define ROW_ 160                    // 8 pieces * 20
#define OUTQ_OFF ((size_t)B_ * S_ * ROW_)
#define NEG_INF -3.402823466e38f

typedef __attribute__((ext_vector_type(8))) short short8v;   // 8 bf16 = 4 VGPRs
typedef __attribute__((ext_vector_type(4))) float float4v;

__device__ __forceinline__ short f2bf(float x) {   // RNE float->bf16 bits
  unsigned u = __float_as_uint(x);
  u += 0x7fffu + ((u >> 16) & 1u);
  return (short)(u >> 16);
}
__device__ __forceinline__ float bf2f_(short s) {
  return __uint_as_float(((unsigned)(unsigned short)s) << 16);
}

// ---------------- K0: w2t (transposed w^2 for outs) + w1 (|W| for mfma maxpool) + zero sum_p
__global__ void k_w2(const float* __restrict__ Wf, float* __restrict__ w2t,
                     float* __restrict__ w1, float* __restrict__ sum_p) {
  int i = blockIdx.x * 256 + threadIdx.x;
  if (i < 8 * L_ * H_) {
    float v = Wf[i];
    float v2 = v * v;
    w1[i] = fabsf(v);
    int widx = i / (L_ * H_);
    int r = i - widx * (L_ * H_);
    int l = r / H_;
    int h = r - l * H_;
    w2t[widx * (L_ * H_) + h * L_ + l] = v2;
  }
  if (i < B_ * 2 * S_) sum_p[i] = 0.f;
}

// ---------------- K1: cosine matrix, block = (bd, 16-row p-group) (r10-13: pass)
__global__ __launch_bounds__(256) void k_cos(const float* __restrict__ P,
                                             const float* __restrict__ Q,
                                             float* __restrict__ cosM,
                                             float* __restrict__ sum_p,
                                             float* __restrict__ sum_q) {
  int bd = blockIdx.x;
  int pg = blockIdx.y;
  int p0 = pg * 16;
  int b = bd >> 1, dir = bd & 1;
  __shared__ float xp[16][101];
  __shared__ float xq[S_][101];
  __shared__ float pn[16], qn[S_];
  __shared__ float cosL[16][S_ + 1];
  int t = threadIdx.x;
  int q = t & 63, pr = t >> 6;
  float dot[4] = {0.f, 0.f, 0.f, 0.f};
  float np2 = 0.f, nq2 = 0.f;
  const float* Pb = P + (size_t)b * S_ * H2_ + dir * H_;
  const float* Qb = Q + (size_t)b * S_ * H2_ + dir * H_;
  for (int c0 = 0; c0 < H_; c0 += 100) {
    __syncthreads();
    for (int idx = t; idx < 16 * 100; idx += 256) {
      int s = idx / 100, hh = idx - s * 100;
      xp[s][hh] = Pb[(size_t)(p0 + s) * H2_ + c0 + hh];
    }
    for (int idx = t; idx < S_ * 100; idx += 256) {
      int s = idx / 100, hh = idx - s * 100;
      xq[s][hh] = Qb[(size_t)s * H2_ + c0 + hh];
    }
    __syncthreads();
    for (int hh = 0; hh < 100; ++hh) {
      float qv = xq[q][hh];
#pragma unroll
      for (int i = 0; i < 4; ++i) dot[i] = fmaf(xp[pr + 4 * i][hh], qv, dot[i]);
    }
    if (t < 16) {
      for (int hh = 0; hh < 100; ++hh) { float v = xp[t][hh]; np2 = fmaf(v, v, np2); }
    } else if (t >= 64 && t < 128) {
      int s2 = t - 64;
      for (int hh = 0; hh < 100; ++hh) { float v = xq[s2][hh]; nq2 = fmaf(v, v, nq2); }
    }
  }
  if (t < 16) pn[t] = sqrtf(np2);
  else if (t >= 64 && t < 128) qn[t - 64] = sqrtf(nq2);
  __syncthreads();
  float* cm = cosM + (size_t)bd * S_ * S_;
#pragma unroll
  for (int i = 0; i < 4; ++i) {
    int p = pr + 4 * i;
    float c = dot[i] / (pn[p] * qn[q]);
    cosL[p][q] = c;
    cm[(size_t)(p0 + p) * S_ + q] = c;
  }
  __syncthreads();
  if (t < 16) {
    double acc = 0.0;
    for (int qq = 0; qq < S_; ++qq) acc += (double)cosL[t][qq];
    sum_q[bd * S_ + p0 + t] = (float)acc;
  } else if (t >= 64 && t < 128) {
    int qq = t - 64;
    float acc = 0.f;
    for (int p = 0; p < 16; ++p) acc += cosL[p][qq];
    atomicAdd(&sum_p[bd * S_ + qq], acc);
  }
}

// ======== fused main kernel — R14: XCD-aware bid swizzle (all blocks of a bd
// land on one XCD so the 153.6 KB P/Q slab is fetched from HBM once per bd,
// not once per XCD). Math identical to r13.
#define HP 72
struct MaxpoolS {                   // 39600 B
  short ph[S_][HP], pl[S_][HP];
  short qh[S_][HP], ql[S_][HP];
  float w1s[H_];
  float pn[S_], qn[S_];
  float colp[4][S_];
};
#define SG 4
struct OutsS {                      // 31264 B
  float u[600];
  float xP[SG][H_], xQ[SG][H_];
  float vmq[SG][H_], vmp[SG][H_], vxq[SG][H_], vxp[SG][H_];
  float sps[SG], sqs[SG];
};

__device__ __forceinline__ void maxpool_body(char* smem, int bid,
                                             const float* __restrict__ P,
                                             const float* __restrict__ Q,
                                             const float* __restrict__ w1,
                                             float* __restrict__ out) {
  MaxpoolS& S = *(MaxpoolS*)smem;
  // swizzle: bid = 8*j + x, x = XCD slot; bd = x + 8*(j&7); l = j>>3
  int x = bid & 7, j = bid >> 3;
  int bd = x + 8 * (j & 7);
  int l = j >> 3;
  int b = bd >> 1, dir = bd & 1;
  int t = threadIdx.x;
  int w = t >> 6, lane = t & 63, quad = lane >> 4, col = lane & 15;
  const float* w1g = w1 + (size_t)(2 + dir) * L_ * H_ + (size_t)l * H_;
  for (int idx = t; idx < H_; idx += 256) S.w1s[idx] = w1g[idx];
  const float* Pb = P + (size_t)b * S_ * H2_ + dir * H_;
  const float* Qb = Q + (size_t)b * S_ * H2_ + dir * H_;
  float4v acc[4];
#pragma unroll
  for (int qt = 0; qt < 4; ++qt) acc[qt] = (float4v){0.f, 0.f, 0.f, 0.f};
  float np2 = 0.f, nq2 = 0.f;
  for (int h0 = 0; h0 < H_; h0 += 64) {
    __syncthreads();
    for (int idx = t; idx < S_ * 64; idx += 256) {
      int s = idx >> 6, hh = idx & 63, h = h0 + hh;
      float pv = 0.f, qv = 0.f;
      if (h < H_) {
        float wv = S.w1s[h];
        pv = Pb[(size_t)s * H2_ + h] * wv;
        qv = Qb[(size_t)s * H2_ + h] * wv;
      }
      short phi = f2bf(pv), qhi = f2bf(qv);
      S.ph[s][hh] = phi; S.pl[s][hh] = f2bf(pv - bf2f_(phi));
      S.qh[s][hh] = qhi; S.ql[s][hh] = f2bf(qv - bf2f_(qhi));
    }
    __syncthreads();
#pragma unroll
    for (int ks = 0; ks < 2; ++ks) {
      short8v ah = *(const short8v*)&S.ph[16 * w + col][ks * 32 + quad * 8];
      short8v al = *(const short8v*)&S.pl[16 * w + col][ks * 32 + quad * 8];
#pragma unroll
      for (int qt = 0; qt < 4; ++qt) {
        short8v bh = *(const short8v*)&S.qh[16 * qt + col][ks * 32 + quad * 8];
        short8v bl = *(const short8v*)&S.ql[16 * qt + col][ks * 32 + quad * 8];
        acc[qt] = __builtin_amdgcn_mfma_f32_16x16x32_bf16(ah, bh, acc[qt], 0, 0, 0);
        acc[qt] = __builtin_amdgcn_mfma_f32_16x16x32_bf16(ah, bl, acc[qt], 0, 0, 0);
        acc[qt] = __builtin_amdgcn_mfma_f32_16x16x32_bf16(al, bh, acc[qt], 0, 0, 0);
      }
    }
    if (t < S_) {
      for (int hh = 0; hh < 64; ++hh) {
        float v = bf2f_(S.ph[t][hh]) + bf2f_(S.pl[t][hh]);
        np2 = fmaf(v, v, np2);
      }
    } else if (t < 2 * S_) {
      int s2 = t - S_;
      for (int hh = 0; hh < 64; ++hh) {
        float v = bf2f_(S.qh[s2][hh]) + bf2f_(S.ql[s2][hh]);
        nq2 = fmaf(v, v, nq2);
      }
    }
  }
  if (t < S_) S.pn[t] = sqrtf(np2);
  else if (t < 2 * S_) S.qn[t - S_] = sqrtf(nq2);
  __syncthreads();
  float pnv[4];
#pragma unroll
  for (int r = 0; r < 4; ++r) pnv[r] = S.pn[16 * w + quad * 4 + r];
  float rowm[4] = {NEG_INF, NEG_INF, NEG_INF, NEG_INF};
#pragma unroll
  for (int qt = 0; qt < 4; ++qt) {
    float qnv = S.qn[16 * qt + col];
    float cm = NEG_INF;
#pragma unroll
    for (int r = 0; r < 4; ++r) {
      float c = acc[qt][r] / (pnv[r] * qnv);    // no EPS in reference maxpool
      rowm[r] = fmaxf(rowm[r], c);
      cm = fmaxf(cm, c);
    }
    cm = fmaxf(cm, __shfl_xor(cm, 16));
    cm = fmaxf(cm, __shfl_xor(cm, 32));
    if (quad == 0) S.colp[w][16 * qt + col] = cm;
  }
#pragma unroll
  for (int m = 1; m < 16; m <<= 1)
#pragma unroll
    for (int r = 0; r < 4; ++r) rowm[r] = fmaxf(rowm[r], __shfl_xor(rowm[r], m));
  if (col == 0) {
#pragma unroll
    for (int r = 0; r < 4; ++r) {
      int p = 16 * w + quad * 4 + r;
      out[((size_t)b * S_ + p) * ROW_ + (2 + dir) * L_ + l] = rowm[r];
    }
  }
  __syncthreads();
  if (t < S_) {
    float m0 = fmaxf(fmaxf(S.colp[0][t], S.colp[1][t]), fmaxf(S.colp[2][t], S.colp[3][t]));
    out[OUTQ_OFF + ((size_t)b * S_ + t) * ROW_ + (2 + dir) * L_ + l] = m0;
  }
}

__device__ __forceinline__ void outs_body(char* smem, int bid,
                                          const float* __restrict__ P,
                                          const float* __restrict__ Q,
                                          const float* __restrict__ w2t,
                                          const float* __restrict__ cosM,
                                          const float* __restrict__ sum_p,
                                          const float* __restrict__ sum_q,
                                          float* __restrict__ out) {
  OutsS& S = *(OutsS*)smem;
  // swizzle: bd = (bid&7) + 8*((bid>>3)&7); sg = bid>>6
  int x = bid & 7, j = bid >> 3;
  int bd = x + 8 * (j & 7);
  int sg = j >> 3;
  int s0 = sg * SG;
  int b = bd >> 1, dir = bd & 1;
  int t = threadIdx.x;
  float (*cosC)[S_] = (float (*)[S_])&S.u[0];
  float (*cosR)[S_] = (float (*)[S_])&S.u[256];
  const float* cm = cosM + (size_t)bd * S_ * S_;
  for (int idx = t; idx < SG * S_; idx += 256) {
    int si = idx >> 6, k = idx & 63;
    cosC[si][k] = cm[k * S_ + s0 + si];
    cosR[si][k] = cm[(s0 + si) * S_ + k];
  }
  if (t < SG) { S.sps[t] = sum_p[bd * S_ + s0 + t]; S.sqs[t] = sum_q[bd * S_ + s0 + t]; }
  int tgt = dir ? 0 : S_ - 1;
  const float* Pb = P + (size_t)b * S_ * H2_ + dir * H_;
  const float* Qb = Q + (size_t)b * S_ * H2_ + dir * H_;
  for (int idx = t; idx < SG * H_; idx += 256) {
    int si = idx / H_, h = idx - si * H_;
    S.xP[si][h] = Pb[(size_t)(s0 + si) * H2_ + h];
    S.xQ[si][h] = Qb[(size_t)(s0 + si) * H2_ + h];
  }
  __syncthreads();
  for (int h = t; h < H_; h += 256) {
    float amp[SG], amq[SG], axp[SG], axq[SG];
#pragma unroll
    for (int si = 0; si < SG; ++si) { amp[si] = 0.f; amq[si] = 0.f; axp[si] = NEG_INF; axq[si] = NEG_INF; }
    for (int k = 0; k < S_; k += 2) {
      float pv0 = Pb[(size_t)k * H2_ + h];
      float qv0 = Qb[(size_t)k * H2_ + h];
      float pv1 = Pb[(size_t)(k + 1) * H2_ + h];
      float qv1 = Qb[(size_t)(k + 1) * H2_ + h];
#pragma unroll
      for (int si = 0; si < SG; ++si) {
        float t1 = pv0 * cosC[si][k];
        amp[si] += t1; axp[si] = fmaxf(axp[si], t1);
        float t2 = qv0 * cosR[si][k];
        amq[si] += t2; axq[si] = fmaxf(axq[si], t2);
        float t3 = pv1 * cosC[si][k + 1];
        amp[si] += t3; axp[si] = fmaxf(axp[si], t3);
        float t4 = qv1 * cosR[si][k + 1];
        amq[si] += t4; axq[si] = fmaxf(axq[si], t4);
      }
    }
#pragma unroll
    for (int si = 0; si < SG; ++si) {
      S.vmq[si][h] = amq[si] / S.sqs[si];
      S.vmp[si][h] = amp[si] / S.sps[si];
      S.vxq[si][h] = axq[si];
      S.vxp[si][h] = axp[si];
    }
  }
  __syncthreads();
  float* tq = &S.u[0];
  float* tp = &S.u[300];
  for (int h = t; h < H_; h += 256) { tq[h] = Qb[(size_t)tgt * H2_ + h]; tp[h] = Pb[(size_t)tgt * H2_ + h]; }
  __syncthreads();
  if (t < 240) {
    const int wb_[6] = {0, 0, 4, 4, 6, 6};
#pragma unroll
    for (int r = 0; r < 2; ++r) {
      int job = t + 240 * r;
      int l = job % L_;
      int g = job / L_;
      int pr = g % 6, si = g / 6;
      const float* xv = (pr & 1) ? S.xQ[si] : S.xP[si];
      const float* y;
      if (pr == 0) y = tq;
      else if (pr == 1) y = tp;
      else if (pr == 2) y = S.vmq[si];
      else if (pr == 3) y = S.vmp[si];
      else if (pr == 4) y = S.vxq[si];
      else y = S.vxp[si];
      int widx = wb_[pr] + dir;
      const float* wp = w2t + (size_t)widx * (L_ * H_) + l;
      float a1 = 0.f, a2 = 0.f, a3 = 0.f;
      for (int h = 0; h < H_; ++h) {
        float wv = wp[h * L_];
        float xx = xv[h], yy = y[h];
        float wx = wv * xx;
        a1 = fmaf(wx, yy, a1);
        a2 = fmaf(wx, xx, a2);
        a3 = fmaf(wv * yy, yy, a3);
      }
      float den = fmaxf(sqrtf(a2) * sqrtf(a3), 1e-8f);   // EPS per _mp_cos
      float c = a1 / den;
      int s = s0 + si;
      size_t base = ((pr & 1) ? OUTQ_OFF : 0) + ((size_t)b * S_ + s) * ROW_;
      out[base + (size_t)widx * L_ + l] = c;
    }
  }
}

__global__ __launch_bounds__(256) void k_main(const float* __restrict__ P,
                                              const float* __restrict__ Q,
                                              const float* __restrict__ w1,
                                              const float* __restrict__ w2t,
                                              const float* __restrict__ cosM,
                                              const float* __restrict__ sum_p,
                                              const float* __restrict__ sum_q,
                                              float* __restrict__ out) {
  extern __shared__ char smem[];
  int bid = blockIdx.x;
  if (bid < B_ * 2 * L_) maxpool_body(smem, bid, P, Q, w1, out);
  else outs_body(smem, bid - B_ * 2 * L_, P, Q, w2t, cosM, sum_p, sum_q, out);
}

extern "C" void kernel_launch(void* const* d_in, const int* in_sizes, int n_in,
                              void* d_out, int out_size, void* d_ws, size_t ws_size,
                              hipStream_t stream) {
  (void)out_size; (void)ws_size;
  int iw = 2;
  for (int i = 0; i < n_in; ++i) if (in_sizes[i] == 8 * L_ * H_) iw = i;
  int io[2] = {0, 1}, k = 0;
  for (int i = 0; i < n_in && k < 2; ++i) if (i != iw) io[k++] = i;
  const float* P  = (const float*)d_in[io[0]];
  const float* Q  = (const float*)d_in[io[1]];
  const float* Wf = (const float*)d_in[iw];
  float* out = (float*)d_out;

  float* ws = (float*)d_ws;         // ~1.46 MB
  float* w2t   = ws;                // 48000
  float* w1    = w2t + 48000;       // 48000
  float* cosM  = w1 + 48000;        // 262144
  float* sum_p = cosM + 262144;     // 4096 (zeroed by k_w2, atomic target)
  float* sum_q = sum_p + 4096;      // 4096

  size_t shbytes = sizeof(MaxpoolS) > sizeof(OutsS) ? sizeof(MaxpoolS) : sizeof(OutsS);
  k_w2<<<(8 * L_ * H_ + 255) / 256, 256, 0, stream>>>(Wf, w2t, w1, sum_p);
  k_cos<<<dim3(B_ * 2, 4), 256, 0, stream>>>(P, Q, cosM, sum_p, sum_q);
  k_main<<<B_ * 2 * L_ + B_ * 2 * 16, 256, shbytes, stream>>>(P, Q, w1, w2t, cosM, sum_p, sum_q, out);
}

// Round 15
// 165.586 us; speedup vs baseline: 1.2836x; 1.0744x over previous
//
#include <hip/hip_runtime.h>
#include <hip/hip_bf16.h>

#define B_ 32
#define S_ 64
#define H_ 300
#define H2_ 600
#define L_ 20
#define ROW_ 160                    // 8 pieces * 20
#define OUTQ_OFF ((size_t)B_ * S_ * ROW_)
#define NEG_INF -3.402823466e38f

typedef __attribute__((ext_vector_type(8))) _Float16 half8v;   // 8 f16 = 4 VGPRs
typedef __attribute__((ext_vector_type(4))) float float4v;

// ---------------- K0: w2t (transposed w^2 for outs) + w1 (|W| for mfma maxpool) + zero sum_p
__global__ void k_w2(const float* __restrict__ Wf, float* __restrict__ w2t,
                     float* __restrict__ w1, float* __restrict__ sum_p) {
  int i = blockIdx.x * 256 + threadIdx.x;
  if (i < 8 * L_ * H_) {
    float v = Wf[i];
    float v2 = v * v;
    w1[i] = fabsf(v);
    int widx = i / (L_ * H_);
    int r = i - widx * (L_ * H_);
    int l = r / H_;
    int h = r - l * H_;
    w2t[widx * (L_ * H_) + h * L_ + l] = v2;
  }
  if (i < B_ * 2 * S_) sum_p[i] = 0.f;
}

// ---------------- K1: cosine matrix, block = (bd, 16-row p-group) (r10-14: pass)
__global__ __launch_bounds__(256) void k_cos(const float* __restrict__ P,
                                             const float* __restrict__ Q,
                                             float* __restrict__ cosM,
                                             float* __restrict__ sum_p,
                                             float* __restrict__ sum_q) {
  int bd = blockIdx.x;
  int pg = blockIdx.y;
  int p0 = pg * 16;
  int b = bd >> 1, dir = bd & 1;
  __shared__ float xp[16][101];
  __shared__ float xq[S_][101];
  __shared__ float pn[16], qn[S_];
  __shared__ float cosL[16][S_ + 1];
  int t = threadIdx.x;
  int q = t & 63, pr = t >> 6;
  float dot[4] = {0.f, 0.f, 0.f, 0.f};
  float np2 = 0.f, nq2 = 0.f;
  const float* Pb = P + (size_t)b * S_ * H2_ + dir * H_;
  const float* Qb = Q + (size_t)b * S_ * H2_ + dir * H_;
  for (int c0 = 0; c0 < H_; c0 += 100) {
    __syncthreads();
    for (int idx = t; idx < 16 * 100; idx += 256) {
      int s = idx / 100, hh = idx - s * 100;
      xp[s][hh] = Pb[(size_t)(p0 + s) * H2_ + c0 + hh];
    }
    for (int idx = t; idx < S_ * 100; idx += 256) {
      int s = idx / 100, hh = idx - s * 100;
      xq[s][hh] = Qb[(size_t)s * H2_ + c0 + hh];
    }
    __syncthreads();
    for (int hh = 0; hh < 100; ++hh) {
      float qv = xq[q][hh];
#pragma unroll
      for (int i = 0; i < 4; ++i) dot[i] = fmaf(xp[pr + 4 * i][hh], qv, dot[i]);
    }
    if (t < 16) {
      for (int hh = 0; hh < 100; ++hh) { float v = xp[t][hh]; np2 = fmaf(v, v, np2); }
    } else if (t >= 64 && t < 128) {
      int s2 = t - 64;
      for (int hh = 0; hh < 100; ++hh) { float v = xq[s2][hh]; nq2 = fmaf(v, v, nq2); }
    }
  }
  if (t < 16) pn[t] = sqrtf(np2);
  else if (t >= 64 && t < 128) qn[t - 64] = sqrtf(nq2);
  __syncthreads();
  float* cm = cosM + (size_t)bd * S_ * S_;
#pragma unroll
  for (int i = 0; i < 4; ++i) {
    int p = pr + 4 * i;
    float c = dot[i] / (pn[p] * qn[q]);
    cosL[p][q] = c;
    cm[(size_t)(p0 + p) * S_ + q] = c;
  }
  __syncthreads();
  if (t < 16) {
    double acc = 0.0;
    for (int qq = 0; qq < S_; ++qq) acc += (double)cosL[t][qq];
    sum_q[bd * S_ + p0 + t] = (float)acc;
  } else if (t >= 64 && t < 128) {
    int qq = t - 64;
    float acc = 0.f;
    for (int p = 0; p < 16; ++p) acc += cosL[p][qq];
    atomicAdd(&sum_p[bd * S_ + qq], acc);
  }
}

// ======== fused main kernel — R15: maxpool on single-fp16 MFMA (1 mfma per
// product, ~4 ops/element convert vs 12 for split-bf16) + XCD swizzle (r14).
#define HP 72                       // padded row: 144 B, 16-B aligned f16x8 groups
struct MaxpoolS {                   // ~21.4 KB
  _Float16 ph[S_][HP];              // w-scaled P, fp16
  _Float16 qh[S_][HP];              // w-scaled Q, fp16
  float w1s[H_];
  float pn[S_], qn[S_];
  float colp[4][S_];
};
#define SG 4
struct OutsS {                      // 31264 B (unchanged, occupancy bound: 5/CU)
  float u[600];
  float xP[SG][H_], xQ[SG][H_];
  float vmq[SG][H_], vmp[SG][H_], vxq[SG][H_], vxp[SG][H_];
  float sps[SG], sqs[SG];
};

__device__ __forceinline__ void maxpool_body(char* smem, int bid,
                                             const float* __restrict__ P,
                                             const float* __restrict__ Q,
                                             const float* __restrict__ w1,
                                             float* __restrict__ out) {
  MaxpoolS& S = *(MaxpoolS*)smem;
  // XCD swizzle: bd = (bid&7) + 8*((bid>>3)&7); l = bid>>6
  int x = bid & 7, j = bid >> 3;
  int bd = x + 8 * (j & 7);
  int l = j >> 3;
  int b = bd >> 1, dir = bd & 1;
  int t = threadIdx.x;
  int w = t >> 6, lane = t & 63, quad = lane >> 4, col = lane & 15;
  const float* w1g = w1 + (size_t)(2 + dir) * L_ * H_ + (size_t)l * H_;
  for (int idx = t; idx < H_; idx += 256) S.w1s[idx] = w1g[idx];
  const float* Pb = P + (size_t)b * S_ * H2_ + dir * H_;
  const float* Qb = Q + (size_t)b * S_ * H2_ + dir * H_;
  float4v acc[4];
#pragma unroll
  for (int qt = 0; qt < 4; ++qt) acc[qt] = (float4v){0.f, 0.f, 0.f, 0.f};
  float np2 = 0.f, nq2 = 0.f;
  for (int h0 = 0; h0 < H_; h0 += 64) {          // 5 chunks (last zero-padded)
    __syncthreads();
    for (int idx = t; idx < S_ * 64; idx += 256) {
      int s = idx >> 6, hh = idx & 63, h = h0 + hh;
      float pv = 0.f, qv = 0.f;
      if (h < H_) {
        float wv = S.w1s[h];
        pv = Pb[(size_t)s * H2_ + h] * wv;
        qv = Qb[(size_t)s * H2_ + h] * wv;
      }
      S.ph[s][hh] = (_Float16)pv;
      S.qh[s][hh] = (_Float16)qv;
    }
    __syncthreads();
#pragma unroll
    for (int ks = 0; ks < 2; ++ks) {
      half8v ah = *(const half8v*)&S.ph[16 * w + col][ks * 32 + quad * 8];
#pragma unroll
      for (int qt = 0; qt < 4; ++qt) {
        half8v bh = *(const half8v*)&S.qh[16 * qt + col][ks * 32 + quad * 8];
        acc[qt] = __builtin_amdgcn_mfma_f32_16x16x32_f16(ah, bh, acc[qt], 0, 0, 0);
      }
    }
    if (t < S_) {               // norms from the SAME fp16 values (consistent)
      for (int hh = 0; hh < 64; ++hh) {
        float v = (float)S.ph[t][hh];
        np2 = fmaf(v, v, np2);
      }
    } else if (t < 2 * S_) {
      int s2 = t - S_;
      for (int hh = 0; hh < 64; ++hh) {
        float v = (float)S.qh[s2][hh];
        nq2 = fmaf(v, v, nq2);
      }
    }
  }
  if (t < S_) S.pn[t] = sqrtf(np2);
  else if (t < 2 * S_) S.qn[t - S_] = sqrtf(nq2);
  __syncthreads();
  // C/D: row = quad*4+r (p_local), col = lane&15 (q_local) [m89/m91 verified]
  float pnv[4];
#pragma unroll
  for (int r = 0; r < 4; ++r) pnv[r] = S.pn[16 * w + quad * 4 + r];
  float rowm[4] = {NEG_INF, NEG_INF, NEG_INF, NEG_INF};
#pragma unroll
  for (int qt = 0; qt < 4; ++qt) {
    float qnv = S.qn[16 * qt + col];
    float cm = NEG_INF;
#pragma unroll
    for (int r = 0; r < 4; ++r) {
      float c = acc[qt][r] / (pnv[r] * qnv);    // no EPS in reference maxpool
      rowm[r] = fmaxf(rowm[r], c);
      cm = fmaxf(cm, c);
    }
    cm = fmaxf(cm, __shfl_xor(cm, 16));
    cm = fmaxf(cm, __shfl_xor(cm, 32));
    if (quad == 0) S.colp[w][16 * qt + col] = cm;
  }
#pragma unroll
  for (int m = 1; m < 16; m <<= 1)
#pragma unroll
    for (int r = 0; r < 4; ++r) rowm[r] = fmaxf(rowm[r], __shfl_xor(rowm[r], m));
  if (col == 0) {
#pragma unroll
    for (int r = 0; r < 4; ++r) {
      int p = 16 * w + quad * 4 + r;
      out[((size_t)b * S_ + p) * ROW_ + (2 + dir) * L_ + l] = rowm[r];
    }
  }
  __syncthreads();
  if (t < S_) {
    float m0 = fmaxf(fmaxf(S.colp[0][t], S.colp[1][t]), fmaxf(S.colp[2][t], S.colp[3][t]));
    out[OUTQ_OFF + ((size_t)b * S_ + t) * ROW_ + (2 + dir) * L_ + l] = m0;
  }
}

__device__ __forceinline__ void outs_body(char* smem, int bid,
                                          const float* __restrict__ P,
                                          const float* __restrict__ Q,
                                          const float* __restrict__ w2t,
                                          const float* __restrict__ cosM,
                                          const float* __restrict__ sum_p,
                                          const float* __restrict__ sum_q,
                                          float* __restrict__ out) {
  OutsS& S = *(OutsS*)smem;
  // XCD swizzle: bd = (bid&7) + 8*((bid>>3)&7); sg = bid>>6
  int x = bid & 7, j = bid >> 3;
  int bd = x + 8 * (j & 7);
  int sg = j >> 3;
  int s0 = sg * SG;
  int b = bd >> 1, dir = bd & 1;
  int t = threadIdx.x;
  float (*cosC)[S_] = (float (*)[S_])&S.u[0];
  float (*cosR)[S_] = (float (*)[S_])&S.u[256];
  const float* cm = cosM + (size_t)bd * S_ * S_;
  for (int idx = t; idx < SG * S_; idx += 256) {
    int si = idx >> 6, k = idx & 63;
    cosC[si][k] = cm[k * S_ + s0 + si];
    cosR[si][k] = cm[(s0 + si) * S_ + k];
  }
  if (t < SG) { S.sps[t] = sum_p[bd * S_ + s0 + t]; S.sqs[t] = sum_q[bd * S_ + s0 + t]; }
  int tgt = dir ? 0 : S_ - 1;
  const float* Pb = P + (size_t)b * S_ * H2_ + dir * H_;
  const float* Qb = Q + (size_t)b * S_ * H2_ + dir * H_;
  for (int idx = t; idx < SG * H_; idx += 256) {
    int si = idx / H_, h = idx - si * H_;
    S.xP[si][h] = Pb[(size_t)(s0 + si) * H2_ + h];
    S.xQ[si][h] = Qb[(size_t)(s0 + si) * H2_ + h];
  }
  __syncthreads();
  for (int h = t; h < H_; h += 256) {
    float amp[SG], amq[SG], axp[SG], axq[SG];
#pragma unroll
    for (int si = 0; si < SG; ++si) { amp[si] = 0.f; amq[si] = 0.f; axp[si] = NEG_INF; axq[si] = NEG_INF; }
    for (int k = 0; k < S_; k += 2) {
      float pv0 = Pb[(size_t)k * H2_ + h];
      float qv0 = Qb[(size_t)k * H2_ + h];
      float pv1 = Pb[(size_t)(k + 1) * H2_ + h];
      float qv1 = Qb[(size_t)(k + 1) * H2_ + h];
#pragma unroll
      for (int si = 0; si < SG; ++si) {
        float t1 = pv0 * cosC[si][k];
        amp[si] += t1; axp[si] = fmaxf(axp[si], t1);
        float t2 = qv0 * cosR[si][k];
        amq[si] += t2; axq[si] = fmaxf(axq[si], t2);
        float t3 = pv1 * cosC[si][k + 1];
        amp[si] += t3; axp[si] = fmaxf(axp[si], t3);
        float t4 = qv1 * cosR[si][k + 1];
        amq[si] += t4; axq[si] = fmaxf(axq[si], t4);
      }
    }
#pragma unroll
    for (int si = 0; si < SG; ++si) {
      S.vmq[si][h] = amq[si] / S.sqs[si];
      S.vmp[si][h] = amp[si] / S.sps[si];
      S.vxq[si][h] = axq[si];
      S.vxp[si][h] = axp[si];
    }
  }
  __syncthreads();
  float* tq = &S.u[0];
  float* tp = &S.u[300];
  for (int h = t; h < H_; h += 256) { tq[h] = Qb[(size_t)tgt * H2_ + h]; tp[h] = Pb[(size_t)tgt * H2_ + h]; }
  __syncthreads();
  if (t < 240) {
    const int wb_[6] = {0, 0, 4, 4, 6, 6};
#pragma unroll
    for (int r = 0; r < 2; ++r) {
      int job = t + 240 * r;
      int l = job % L_;
      int g = job / L_;
      int pr = g % 6, si = g / 6;
      const float* xv = (pr & 1) ? S.xQ[si] : S.xP[si];
      const float* y;
      if (pr == 0) y = tq;
      else if (pr == 1) y = tp;
      else if (pr == 2) y = S.vmq[si];
      else if (pr == 3) y = S.vmp[si];
      else if (pr == 4) y = S.vxq[si];
      else y = S.vxp[si];
      int widx = wb_[pr] + dir;
      const float* wp = w2t + (size_t)widx * (L_ * H_) + l;
      float a1 = 0.f, a2 = 0.f, a3 = 0.f;
      for (int h = 0; h < H_; ++h) {
        float wv = wp[h * L_];
        float xx = xv[h], yy = y[h];
        float wx = wv * xx;
        a1 = fmaf(wx, yy, a1);
        a2 = fmaf(wx, xx, a2);
        a3 = fmaf(wv * yy, yy, a3);
      }
      float den = fmaxf(sqrtf(a2) * sqrtf(a3), 1e-8f);   // EPS per _mp_cos
      float c = a1 / den;
      int s = s0 + si;
      size_t base = ((pr & 1) ? OUTQ_OFF : 0) + ((size_t)b * S_ + s) * ROW_;
      out[base + (size_t)widx * L_ + l] = c;
    }
  }
}

__global__ __launch_bounds__(256) void k_main(const float* __restrict__ P,
                                              const float* __restrict__ Q,
                                              const float* __restrict__ w1,
                                              const float* __restrict__ w2t,
                                              const float* __restrict__ cosM,
                                              const float* __restrict__ sum_p,
                                              const float* __restrict__ sum_q,
                                              float* __restrict__ out) {
  extern __shared__ char smem[];
  int bid = blockIdx.x;
  if (bid < B_ * 2 * L_) maxpool_body(smem, bid, P, Q, w1, out);
  else outs_body(smem, bid - B_ * 2 * L_, P, Q, w2t, cosM, sum_p, sum_q, out);
}

extern "C" void kernel_launch(void* const* d_in, const int* in_sizes, int n_in,
                              void* d_out, int out_size, void* d_ws, size_t ws_size,
                              hipStream_t stream) {
  (void)out_size; (void)ws_size;
  int iw = 2;
  for (int i = 0; i < n_in; ++i) if (in_sizes[i] == 8 * L_ * H_) iw = i;
  int io[2] = {0, 1}, k = 0;
  for (int i = 0; i < n_in && k < 2; ++i) if (i != iw) io[k++] = i;
  const float* P  = (const float*)d_in[io[0]];
  const float* Q  = (const float*)d_in[io[1]];
  const float* Wf = (const float*)d_in[iw];
  float* out = (float*)d_out;

  float* ws = (float*)d_ws;         // ~1.46 MB
  float* w2t   = ws;                // 48000
  float* w1    = w2t + 48000;       // 48000
  float* cosM  = w1 + 48000;        // 262144
  float* sum_p = cosM + 262144;     // 4096 (zeroed by k_w2, atomic target)
  float* sum_q = sum_p + 4096;      // 4096

  size_t shbytes = sizeof(MaxpoolS) > sizeof(OutsS) ? sizeof(MaxpoolS) : sizeof(OutsS);
  k_w2<<<(8 * L_ * H_ + 255) / 256, 256, 0, stream>>>(Wf, w2t, w1, sum_p);
  k_cos<<<dim3(B_ * 2, 4), 256, 0, stream>>>(P, Q, cosM, sum_p, sum_q);
  k_main<<<B_ * 2 * L_ + B_ * 2 * 16, 256, shbytes, stream>>>(P, Q, w1, w2t, cosM, sum_p, sum_q, out);
}